// Round 12
// baseline (154.076 us; speedup 1.0000x reference)
//
#include <hip/hip_runtime.h>
#include <stdint.h>

// out = dequant( int8(lhs*ls) @ int8(rhs*rs) ) / (ls*rs), 4096^3, fp32 in/out.
// ls = 127 / max(amax|lhs|, 1e-12). Int core is bit-exact vs numpy (RNE quant).
//
// Workspace: [0,16Mi) qA frag-layout ; [16Mi,32Mi) qBT frag-layout ; 2x u32 amax.
//
// GEMM v11 = v10 (no-LDS fragment-direct: quant emits qA/qBT in MFMA-fragment
// order, GEMM loads frags with coalesced global_load_dwordx4 straight to
// VGPRs -- no LDS/barriers/waitcnt asm) + v9's FAT WAVES (128x128 wave-tile,
// acc[4][4] int32x16 = 256 AGPRs, proven no-spill at VGPR_Count 156).
// Why: v10's counters (LDS=0, conflicts=0, still 86 us / 31% MfmaUtil)
// isolate the per-CU VMEM pipe as the wall: 8 thin waves x 6 KB/slice =
// 96k cyc of L1 time vs 75k cyc MFMA. Bytes/MFMA = (m+n)/(m*n) KB for an
// mxn tile of 32x32 frags: 4x2 = 0.75, 4x4 = 0.50 (-33%). At 4 fat waves:
// 32 KB VMEM per 585-cyc MFMA window = 56 B/cyc < 64 B/cyc L1 peak -> MFMA
// becomes the longer pole. 1 wave/SIMD; 16-MFMA window (585 cyc) covers L2
// latency with the 2-deep slice pipeline; accs independent so a single wave
// saturates the MFMA pipe.
//
// Fragment layouts (verified v8/v9/v10, absmax 0.0):
//   A: byte ((mt_g*128+ks_g)*64 + l)*16 + j = qA8[mt_g*32+(l&31)][ks_g*32+(l>>5)*16+j]
//   B: byte ((nt_g*128+ks_g)*64 + l)*16 + j = qBT8[nt_g*32+(l&31)][ks_g*32+(l>>5)*16+j]
//   C/D: col = lane&31, row = (reg&3) + 8*(reg>>2) + 4*(lane>>5).

#define NROW 4096
#define NELEM (4096 * 4096)

typedef __attribute__((ext_vector_type(4))) int int32x4;
typedef __attribute__((ext_vector_type(16))) int int32x16;

__global__ void absmax_both_kernel(const float* __restrict__ lhs,
                                   const float* __restrict__ rhs,
                                   unsigned* __restrict__ amax) {
    __shared__ float red[4];
    const int t = blockIdx.x & 1;
    const float4* x4 = (const float4*)(t ? rhs : lhs);
    const int bid = blockIdx.x >> 1;
    const int stride = (gridDim.x >> 1) * blockDim.x;  // 262144
    int i = bid * blockDim.x + threadIdx.x;
    float m0 = 0.0f, m1 = 0.0f, m2 = 0.0f, m3 = 0.0f;
    for (; i + 3 * stride < NELEM / 4; i += 4 * stride) {
        float4 a = x4[i];
        float4 b = x4[i + stride];
        float4 c = x4[i + 2 * stride];
        float4 d = x4[i + 3 * stride];
        m0 = fmaxf(m0, fmaxf(fmaxf(fabsf(a.x), fabsf(a.y)),
                             fmaxf(fabsf(a.z), fabsf(a.w))));
        m1 = fmaxf(m1, fmaxf(fmaxf(fabsf(b.x), fabsf(b.y)),
                             fmaxf(fabsf(b.z), fabsf(b.w))));
        m2 = fmaxf(m2, fmaxf(fmaxf(fabsf(c.x), fabsf(c.y)),
                             fmaxf(fabsf(c.z), fabsf(c.w))));
        m3 = fmaxf(m3, fmaxf(fmaxf(fabsf(d.x), fabsf(d.y)),
                             fmaxf(fabsf(d.z), fabsf(d.w))));
    }
    for (; i < NELEM / 4; i += stride) {
        float4 a = x4[i];
        m0 = fmaxf(m0, fmaxf(fmaxf(fabsf(a.x), fabsf(a.y)),
                             fmaxf(fabsf(a.z), fabsf(a.w))));
    }
    float m = fmaxf(fmaxf(m0, m1), fmaxf(m2, m3));
    for (int off = 32; off > 0; off >>= 1)
        m = fmaxf(m, __shfl_down(m, off, 64));
    const int lane = threadIdx.x & 63, wave = threadIdx.x >> 6;
    if (lane == 0) red[wave] = m;
    __syncthreads();
    if (threadIdx.x == 0) {
        float b = fmaxf(fmaxf(red[0], red[1]), fmaxf(red[2], red[3]));
        atomicMax(amax + t, __float_as_uint(b));  // |x|>=0: bits monotone as uint
    }
}

__device__ __forceinline__ int q8(float v, float s) {
    int r = __float2int_rn(v * s);  // RNE, matches jnp.round
    r = r < -127 ? -127 : r;
    r = r > 127 ? 127 : r;
    return r;
}

__device__ __forceinline__ int pack4(float a, float b, float c, float d,
                                     float s) {
    return (q8(a, s) & 0xff) | ((q8(b, s) & 0xff) << 8) |
           ((q8(c, s) & 0xff) << 16) | ((q8(d, s) & 0xff) << 24);
}

// Blocks [0,4096): A -> fragment layout (thread t = chunk c: contiguous 16B
// store to qA+c*16 from 64B row-segment of lhs). Blocks [4096,8192): B ->
// verified LDS 64x64 transpose, frag-order output.
__global__ void quant_kernel(const float* __restrict__ lhs,
                             const float* __restrict__ rhs,
                             int8_t* __restrict__ qA, int8_t* __restrict__ qT,
                             const unsigned* __restrict__ amax) {
    __shared__ int8_t sm[64][68];
    if (blockIdx.x < 4096) {
        const float s = 127.0f / fmaxf(__uint_as_float(amax[0]), 1e-12f);
        const int c = blockIdx.x * 256 + threadIdx.x;
        const int l = c & 63;
        const int ks_g = (c >> 6) & 127;
        const int mt_g = c >> 13;
        const int row = mt_g * 32 + (l & 31);
        const int kb = ks_g * 32 + (l >> 5) * 16;
        const float4* src = (const float4*)(lhs + (size_t)row * NROW + kb);
        float4 v0 = src[0], v1 = src[1], v2 = src[2], v3 = src[3];
        int4 w;
        w.x = pack4(v0.x, v0.y, v0.z, v0.w, s);
        w.y = pack4(v1.x, v1.y, v1.z, v1.w, s);
        w.z = pack4(v2.x, v2.y, v2.z, v2.w, s);
        w.w = pack4(v3.x, v3.y, v3.z, v3.w, s);
        *(int4*)(qA + (size_t)c * 16) = w;
    } else {
        const float s = 127.0f / fmaxf(__uint_as_float(amax[1]), 1e-12f);
        const int b = blockIdx.x - 4096;
        const int n0 = (b & 63) * 64, k0 = (b >> 6) * 64;
        const int rl = threadIdx.x >> 4;   // k row within 16-row slab
        const int nq = threadIdx.x & 15;   // float4 column
        for (int r = 0; r < 4; ++r) {
            const int kl = r * 16 + rl;
            float4 v = *(const float4*)(rhs + (size_t)(k0 + kl) * NROW + n0 + nq * 4);
            sm[nq * 4 + 0][kl] = (int8_t)q8(v.x, s);
            sm[nq * 4 + 1][kl] = (int8_t)q8(v.y, s);
            sm[nq * 4 + 2][kl] = (int8_t)q8(v.z, s);
            sm[nq * 4 + 3][kl] = (int8_t)q8(v.w, s);
        }
        __syncthreads();
        // Frag-order store: tile = 2 nt x 2 ks x 64 lanes = 256 chunks.
        const int nt_l = threadIdx.x >> 7;        // 0..1
        const int ks_l = (threadIdx.x >> 6) & 1;  // 0..1
        const int l = threadIdx.x & 63;
        const int n_loc = nt_l * 32 + (l & 31);
        const int k_loc = ks_l * 32 + (l >> 5) * 16;
        int4 w;  // 4x b32 reads, stride 17 words -> conflict-free
        w.x = *(const int*)&sm[n_loc][k_loc + 0];
        w.y = *(const int*)&sm[n_loc][k_loc + 4];
        w.z = *(const int*)&sm[n_loc][k_loc + 8];
        w.w = *(const int*)&sm[n_loc][k_loc + 12];
        const int nt_g = (b & 63) * 2 + nt_l;
        const int ks_g = (b >> 6) * 2 + ks_l;
        *(int4*)(qT + (((size_t)nt_g * 128 + ks_g) * 64 + l) * 16) = w;
    }
}

// 256x256 tile, 4 waves (2Mx2N of 128x128 = 4x4 of 32x32), no LDS, no
// barriers, 1 wave/SIMD. Flat loop over 128 k-slices: load slice s+1 frags
// (8 coalesced global_load_dwordx4) while MFMAing slice s (16 MFMA, 585 cyc
// window >> L2 latency). F0/F1 register alternation via 2-unroll.
__global__ __launch_bounds__(256, 1) void gemm_i8_kernel(
    const int8_t* __restrict__ qA, const int8_t* __restrict__ qBT,
    float* __restrict__ out, const unsigned* __restrict__ amax) {
    const int tid = threadIdx.x;
    const int lane = tid & 63;
    const int wave = tid >> 6;      // 0..3
    const int wm = wave >> 1;       // 0..1 : 128-row sub-tile
    const int wn = wave & 1;        // 0..1 : 128-col sub-tile

    // XCD-aware bijective swizzle (grid 256, 256%8==0): XCD k gets swz ids
    // [32k,32k+32) -> 2 contiguous M-rows: A frags L2-resident per XCD.
    const int bid = blockIdx.y * 16 + blockIdx.x;
    const int swz = (bid & 7) * 32 + (bid >> 3);
    const int m0 = (swz >> 4) * 256, n0 = (swz & 15) * 256;

    const int rl = lane & 31;       // row within a 32-row MFMA tile
    const int hi = lane >> 5;       // k-half selector

    // Per-lane fragment base pointers. Frag (tile_g, ks_g) at
    // ((tile_g*128 + ks_g)*64 + lane)*16; tile step = 131072 B, ks step = 1024 B.
    const int8_t* pa = qA + (size_t)(m0 / 32 + wm * 4) * 131072 + lane * 16;
    const int8_t* pb = qBT + (size_t)(n0 / 32 + wn * 4) * 131072 + lane * 16;

    int32x16 acc[4][4];
#pragma unroll
    for (int mt = 0; mt < 4; ++mt)
#pragma unroll
        for (int nt = 0; nt < 4; ++nt) acc[mt][nt] = (int32x16)(0);

    int32x4 a0[4], b0[4], a1[4], b1[4];

#define LOADF(A, B, S)                                                        \
    {                                                                         \
        const int8_t* ap = pa + (S)*1024;                                     \
        const int8_t* bp = pb + (S)*1024;                                     \
        A[0] = *(const int32x4*)(ap);                                         \
        A[1] = *(const int32x4*)(ap + 131072);                                \
        A[2] = *(const int32x4*)(ap + 262144);                                \
        A[3] = *(const int32x4*)(ap + 393216);                                \
        B[0] = *(const int32x4*)(bp);                                         \
        B[1] = *(const int32x4*)(bp + 131072);                                \
        B[2] = *(const int32x4*)(bp + 262144);                                \
        B[3] = *(const int32x4*)(bp + 393216);                                \
    }

#define MFMAF(A, B)                                                           \
    {                                                                         \
        _Pragma("unroll") for (int mt = 0; mt < 4; ++mt)                      \
            _Pragma("unroll") for (int nt = 0; nt < 4; ++nt) acc[mt][nt] =    \
                __builtin_amdgcn_mfma_i32_32x32x32_i8(A[mt], B[nt],           \
                                                      acc[mt][nt], 0, 0, 0);  \
    }

    LOADF(a0, b0, 0)
#pragma unroll 1
    for (int s = 0; s < 126; s += 2) {
        LOADF(a1, b1, s + 1)
        MFMAF(a0, b0)
        LOADF(a0, b0, s + 2)
        MFMAF(a1, b1)
    }
    LOADF(a1, b1, 127)
    MFMAF(a0, b0)  // slice 126
    MFMAF(a1, b1)  // slice 127

    // Epilogue: dequant + store. 32x32 C/D layout: col = lane&31,
    // row = (reg&3) + 8*(reg>>2) + 4*(lane>>5).
    const float ls = 127.0f / fmaxf(__uint_as_float(amax[0]), 1e-12f);
    const float rs = 127.0f / fmaxf(__uint_as_float(amax[1]), 1e-12f);
    const float inv = 1.0f / (ls * rs);
#pragma unroll
    for (int mt = 0; mt < 4; ++mt)
#pragma unroll
        for (int nt = 0; nt < 4; ++nt)
#pragma unroll
            for (int reg = 0; reg < 16; ++reg) {
                const int row = m0 + wm * 128 + mt * 32 + (reg & 3) +
                                8 * (reg >> 2) + 4 * hi;
                const int col = n0 + wn * 128 + nt * 32 + rl;
                out[(size_t)row * NROW + col] = (float)acc[mt][nt][reg] * inv;
            }
#undef LOADF
#undef MFMAF
}

extern "C" void kernel_launch(void* const* d_in, const int* in_sizes, int n_in,
                              void* d_out, int out_size, void* d_ws,
                              size_t ws_size, hipStream_t stream) {
    const float* lhs = (const float*)d_in[0];
    const float* rhs = (const float*)d_in[1];
    float* out = (float*)d_out;

    int8_t* qA = (int8_t*)d_ws;
    int8_t* qBT = qA + (size_t)16 * 1024 * 1024;
    unsigned* amax = (unsigned*)(qBT + (size_t)16 * 1024 * 1024);

    hipMemsetAsync(amax, 0, 8, stream);
    absmax_both_kernel<<<2048, 256, 0, stream>>>(lhs, rhs, amax);
    quant_kernel<<<4096 + 4096, 256, 0, stream>>>(lhs, rhs, qA, qBT, amax);
    gemm_i8_kernel<<<dim3(16, 16), 256, 0, stream>>>(qA, qBT, out, amax);
}

// Round 13
// 137.140 us; speedup vs baseline: 1.1235x; 1.1235x over previous
//
#include <hip/hip_runtime.h>
#include <stdint.h>

// out = dequant( int8(lhs*ls) @ int8(rhs*rs) ) / (ls*rs), 4096^3, fp32 in/out.
// ls = 127 / max(amax|lhs|, 1e-12). Int core is bit-exact vs numpy (RNE quant).
//
// Workspace: [0,16Mi) qA frag-order ; [16Mi,32Mi) qBT frag-order ; 2x u32 amax.
//
// GEMM v12 = v6 skeleton (best measured: 83 us; 256x256 tile, 8 waves of
// 128x64, BK=128 window, double-buffered LDS, prefetch-1, vmcnt(0) on
// window-old loads, one barrier/window, XCD swizzle) + FRAGMENT-ORDERED
// LDS/global + 32x32x32 MFMA. Rationale: v8 showed 32x32x32 is 10% cheaper
// on the MFMA pipe (2342 vs 2613 cyc/CU/window) but row-major LDS makes
// 32-row frag reads 4-way bank-conflicted (6.3M, exactly cancelling). With
// qA/qBT already in fragment order (v10's quant kernels, verified), LDS
// staging is contiguous (global_load_lds: wave-uniform base + lane*16 - the
// exact HW contract) and every ds_read_b128 is frag_base + lane*16: linear,
// ZERO conflicts, zero swizzle; frag select folds into ds_read immediates.
//
// Layouts (all harness-verified, absmax 0.0 in v8/v10/v11):
//   frag (t_g, ks_g) at ((t_g*128 + ks_g)*64 + lane)*16; lane l holds
//   [t_g*32+(l&31)][ks_g*32+(l>>5)*16 .. +16).
//   C/D 32x32: col = lane&31, row = (reg&3) + 8*(reg>>2) + 4*(lane>>5).

#define NROW 4096
#define NELEM (4096 * 4096)

typedef __attribute__((ext_vector_type(4))) int int32x4;
typedef __attribute__((ext_vector_type(16))) int int32x16;
typedef const __attribute__((address_space(1))) int8_t* gptr1_t;
typedef __attribute__((address_space(3))) int8_t* lptr3_t;

__global__ void absmax_both_kernel(const float* __restrict__ lhs,
                                   const float* __restrict__ rhs,
                                   unsigned* __restrict__ amax) {
    __shared__ float red[4];
    const int t = blockIdx.x & 1;
    const float4* x4 = (const float4*)(t ? rhs : lhs);
    const int bid = blockIdx.x >> 1;
    const int stride = (gridDim.x >> 1) * blockDim.x;  // 262144
    int i = bid * blockDim.x + threadIdx.x;
    float m0 = 0.0f, m1 = 0.0f, m2 = 0.0f, m3 = 0.0f;
    for (; i + 3 * stride < NELEM / 4; i += 4 * stride) {
        float4 a = x4[i];
        float4 b = x4[i + stride];
        float4 c = x4[i + 2 * stride];
        float4 d = x4[i + 3 * stride];
        m0 = fmaxf(m0, fmaxf(fmaxf(fabsf(a.x), fabsf(a.y)),
                             fmaxf(fabsf(a.z), fabsf(a.w))));
        m1 = fmaxf(m1, fmaxf(fmaxf(fabsf(b.x), fabsf(b.y)),
                             fmaxf(fabsf(b.z), fabsf(b.w))));
        m2 = fmaxf(m2, fmaxf(fmaxf(fabsf(c.x), fabsf(c.y)),
                             fmaxf(fabsf(c.z), fabsf(c.w))));
        m3 = fmaxf(m3, fmaxf(fmaxf(fabsf(d.x), fabsf(d.y)),
                             fmaxf(fabsf(d.z), fabsf(d.w))));
    }
    for (; i < NELEM / 4; i += stride) {
        float4 a = x4[i];
        m0 = fmaxf(m0, fmaxf(fmaxf(fabsf(a.x), fabsf(a.y)),
                             fmaxf(fabsf(a.z), fabsf(a.w))));
    }
    float m = fmaxf(fmaxf(m0, m1), fmaxf(m2, m3));
    for (int off = 32; off > 0; off >>= 1)
        m = fmaxf(m, __shfl_down(m, off, 64));
    const int lane = threadIdx.x & 63, wave = threadIdx.x >> 6;
    if (lane == 0) red[wave] = m;
    __syncthreads();
    if (threadIdx.x == 0) {
        float b = fmaxf(fmaxf(red[0], red[1]), fmaxf(red[2], red[3]));
        atomicMax(amax + t, __float_as_uint(b));  // |x|>=0: bits monotone as uint
    }
}

__device__ __forceinline__ int q8(float v, float s) {
    int r = __float2int_rn(v * s);  // RNE, matches jnp.round
    r = r < -127 ? -127 : r;
    r = r > 127 ? 127 : r;
    return r;
}

__device__ __forceinline__ int pack4(float a, float b, float c, float d,
                                     float s) {
    return (q8(a, s) & 0xff) | ((q8(b, s) & 0xff) << 8) |
           ((q8(c, s) & 0xff) << 16) | ((q8(d, s) & 0xff) << 24);
}

// Blocks [0,4096): A -> fragment layout (thread t = chunk c: contiguous 16B
// store to qA+c*16 from a 64B row-segment of lhs). Blocks [4096,8192): B ->
// verified LDS 64x64 transpose, frag-order output. (v10/v11-verified.)
__global__ void quant_kernel(const float* __restrict__ lhs,
                             const float* __restrict__ rhs,
                             int8_t* __restrict__ qA, int8_t* __restrict__ qT,
                             const unsigned* __restrict__ amax) {
    __shared__ int8_t sm[64][68];
    if (blockIdx.x < 4096) {
        const float s = 127.0f / fmaxf(__uint_as_float(amax[0]), 1e-12f);
        const int c = blockIdx.x * 256 + threadIdx.x;
        const int l = c & 63;
        const int ks_g = (c >> 6) & 127;
        const int mt_g = c >> 13;
        const int row = mt_g * 32 + (l & 31);
        const int kb = ks_g * 32 + (l >> 5) * 16;
        const float4* src = (const float4*)(lhs + (size_t)row * NROW + kb);
        float4 v0 = src[0], v1 = src[1], v2 = src[2], v3 = src[3];
        int4 w;
        w.x = pack4(v0.x, v0.y, v0.z, v0.w, s);
        w.y = pack4(v1.x, v1.y, v1.z, v1.w, s);
        w.z = pack4(v2.x, v2.y, v2.z, v2.w, s);
        w.w = pack4(v3.x, v3.y, v3.z, v3.w, s);
        *(int4*)(qA + (size_t)c * 16) = w;
    } else {
        const float s = 127.0f / fmaxf(__uint_as_float(amax[1]), 1e-12f);
        const int b = blockIdx.x - 4096;
        const int n0 = (b & 63) * 64, k0 = (b >> 6) * 64;
        const int rl = threadIdx.x >> 4;   // k row within 16-row slab
        const int nq = threadIdx.x & 15;   // float4 column
        for (int r = 0; r < 4; ++r) {
            const int kl = r * 16 + rl;
            float4 v = *(const float4*)(rhs + (size_t)(k0 + kl) * NROW + n0 + nq * 4);
            sm[nq * 4 + 0][kl] = (int8_t)q8(v.x, s);
            sm[nq * 4 + 1][kl] = (int8_t)q8(v.y, s);
            sm[nq * 4 + 2][kl] = (int8_t)q8(v.z, s);
            sm[nq * 4 + 3][kl] = (int8_t)q8(v.w, s);
        }
        __syncthreads();
        // Frag-order store: tile = 2 nt x 2 ks x 64 lanes = 256 chunks.
        const int nt_l = threadIdx.x >> 7;        // 0..1
        const int ks_l = (threadIdx.x >> 6) & 1;  // 0..1
        const int l = threadIdx.x & 63;
        const int n_loc = nt_l * 32 + (l & 31);
        const int k_loc = ks_l * 32 + (l >> 5) * 16;
        int4 w;  // 4x b32 reads, stride 17 words -> conflict-free
        w.x = *(const int*)&sm[n_loc][k_loc + 0];
        w.y = *(const int*)&sm[n_loc][k_loc + 4];
        w.z = *(const int*)&sm[n_loc][k_loc + 8];
        w.w = *(const int*)&sm[n_loc][k_loc + 12];
        const int nt_g = (b & 63) * 2 + nt_l;
        const int ks_g = (b >> 6) * 2 + ks_l;
        *(int4*)(qT + (((size_t)nt_g * 128 + ks_g) * 64 + l) * 16) = w;
    }
}

// 256x256 tile, 8 waves (2Mx4N of 128x64 = 4x2 of 32x32), BK=128, double-
// buffered frag-ordered LDS (2 x 32 KiB x 2 = 128 KiB). Window w: [stage
// tile w+1 -> slot (w+1)&1 (8 gload_lds/thread, contiguous frag blocks);
// compute slot w&1 (4 ks x {6 linear ds_read_b128 + 8 mfma_i32_32x32x32_i8});
// vmcnt(0) (loads a window old -- no stall); s_barrier]. WAR safety: slot
// (w+1)&1 was last read in window w-1, which ended at a barrier.
// LDS map: A-frag (mt_l, ks_l) at (mt_l*4 + ks_l)*1024 + lane*16; B same
// with nt_l. All ds_reads linear in lane -> zero bank conflicts by design.
__global__ __launch_bounds__(512, 2) void gemm_i8_kernel(
    const int8_t* __restrict__ qA, const int8_t* __restrict__ qBT,
    float* __restrict__ out, const unsigned* __restrict__ amax) {
    __shared__ __align__(16) int8_t sA[2][32768];
    __shared__ __align__(16) int8_t sB[2][32768];

    const int tid = threadIdx.x;
    const int lane = tid & 63;
    const int wave = tid >> 6;      // 0..7
    const int wm = wave >> 2;       // 0..1 : 128-row sub-tile
    const int wn = wave & 3;        // 0..3 : 64-col sub-tile

    // XCD-aware bijective swizzle (grid 256, 256%8==0): XCD k gets swz ids
    // [32k,32k+32) -> 2 contiguous M-rows: A frags L2-resident per XCD.
    const int bid = blockIdx.y * 16 + blockIdx.x;
    const int swz = (bid & 7) * 32 + (bid >> 3);
    const int m0 = (swz >> 4) * 256, n0 = (swz & 15) * 256;

    const int rl = lane & 31;       // row within a 32-row MFMA tile
    const int hi = lane >> 5;       // k-half selector

    // Staging: per K-tile, 2048 chunks x 16 B per tensor (8 mt x 4 ks x 64
    // lanes). Thread t, j=0..3: c = t + j*512 -> mt_l = (t>>8) + 2j,
    // rem = t&255 (j-invariant). Global src = frag-ordered qA:
    // (mt0+mt_l)*131072 + kt*4096 + rem*16. LDS dst = slot*32768 + c*16.
    const gptr1_t pA0 = (gptr1_t)(qA + (size_t)(m0 / 32 + (tid >> 8)) * 131072 +
                                  (tid & 255) * 16);
    const gptr1_t pB0 = (gptr1_t)(qBT + (size_t)(n0 / 32 + (tid >> 8)) * 131072 +
                                  (tid & 255) * 16);
    int8_t* sAf = &sA[0][0];
    int8_t* sBf = &sB[0][0];
    const int dst0 = tid * 16;

    auto stage = [&](int slot, int kt) {
        const int kb = kt * 4096;
#pragma unroll
        for (int j = 0; j < 4; ++j) {
            __builtin_amdgcn_global_load_lds(
                pA0 + (size_t)j * 262144 + kb,
                (lptr3_t)(sAf + slot * 32768 + dst0 + j * 8192), 16, 0, 0);
            __builtin_amdgcn_global_load_lds(
                pB0 + (size_t)j * 262144 + kb,
                (lptr3_t)(sBf + slot * 32768 + dst0 + j * 8192), 16, 0, 0);
        }
    };

    int32x16 acc[4][2];
#pragma unroll
    for (int mt = 0; mt < 4; ++mt)
#pragma unroll
        for (int nt = 0; nt < 2; ++nt) acc[mt][nt] = (int32x16)(0);

    // ds_read bases: A-frag (wm*4+mt, ks) at (wm*16+mt*4+ks)*1024 + lane*16;
    // B-frag (wn*2+nt, ks) at (wn*8+nt*4+ks)*1024 + lane*16.
    const int aBase = wm * 16384 + lane * 16;
    const int bBase = wn * 8192 + lane * 16;

    auto compute = [&](const int8_t* a, const int8_t* b) {
#pragma unroll
        for (int ks = 0; ks < 4; ++ks) {
            int32x4 af[4], bf[2];
#pragma unroll
            for (int mt = 0; mt < 4; ++mt)
                af[mt] = *(const int32x4*)(a + aBase + mt * 4096 + ks * 1024);
#pragma unroll
            for (int nt = 0; nt < 2; ++nt)
                bf[nt] = *(const int32x4*)(b + bBase + nt * 4096 + ks * 1024);
            __builtin_amdgcn_s_setprio(1);
#pragma unroll
            for (int mt = 0; mt < 4; ++mt)
#pragma unroll
                for (int nt = 0; nt < 2; ++nt)
                    acc[mt][nt] = __builtin_amdgcn_mfma_i32_32x32x32_i8(
                        af[mt], bf[nt], acc[mt][nt], 0, 0, 0);
            __builtin_amdgcn_s_setprio(0);
        }
    };

    // Prologue: stage tile 0 into slot 0; drain; barrier.
    stage(0, 0);
    asm volatile("s_waitcnt vmcnt(0)" ::: "memory");
    __builtin_amdgcn_sched_barrier(0);
    __builtin_amdgcn_s_barrier();
    __builtin_amdgcn_sched_barrier(0);

    // 32 K-tiles of 128. Windows 0..30 stage the next tile; window 31 below.
#pragma unroll 1
    for (int w = 0; w < 31; ++w) {
        stage((w + 1) & 1, w + 1);
        compute(sAf + (w & 1) * 32768, sBf + (w & 1) * 32768);
        asm volatile("s_waitcnt vmcnt(0)" ::: "memory");
        __builtin_amdgcn_sched_barrier(0);
        __builtin_amdgcn_s_barrier();
        __builtin_amdgcn_sched_barrier(0);
    }
    compute(sAf + 32768, sBf + 32768);  // tile 31, slot 1

    // Epilogue: dequant + store. 32x32 C/D layout: col = lane&31,
    // row = (reg&3) + 8*(reg>>2) + 4*(lane>>5). (v8-verified.)
    const float ls = 127.0f / fmaxf(__uint_as_float(amax[0]), 1e-12f);
    const float rs = 127.0f / fmaxf(__uint_as_float(amax[1]), 1e-12f);
    const float inv = 1.0f / (ls * rs);
#pragma unroll
    for (int mt = 0; mt < 4; ++mt)
#pragma unroll
        for (int nt = 0; nt < 2; ++nt)
#pragma unroll
            for (int reg = 0; reg < 16; ++reg) {
                const int row = m0 + wm * 128 + mt * 32 + (reg & 3) +
                                8 * (reg >> 2) + 4 * hi;
                const int col = n0 + wn * 64 + nt * 32 + rl;
                out[(size_t)row * NROW + col] = (float)acc[mt][nt][reg] * inv;
            }
}

extern "C" void kernel_launch(void* const* d_in, const int* in_sizes, int n_in,
                              void* d_out, int out_size, void* d_ws,
                              size_t ws_size, hipStream_t stream) {
    const float* lhs = (const float*)d_in[0];
    const float* rhs = (const float*)d_in[1];
    float* out = (float*)d_out;

    int8_t* qA = (int8_t*)d_ws;
    int8_t* qBT = qA + (size_t)16 * 1024 * 1024;
    unsigned* amax = (unsigned*)(qBT + (size_t)16 * 1024 * 1024);

    hipMemsetAsync(amax, 0, 8, stream);
    absmax_both_kernel<<<2048, 256, 0, stream>>>(lhs, rhs, amax);
    quant_kernel<<<4096 + 4096, 256, 0, stream>>>(lhs, rhs, qA, qBT, amax);
    gemm_i8_kernel<<<dim3(16, 16), 512, 0, stream>>>(qA, qBT, out, amax);
}